// Round 20
// baseline (170.224 us; speedup 1.0000x reference)
//
#include <hip/hip_runtime.h>
#include <cmath>

// ---------------------------------------------------------------------------
// MHA forward, bf16-MFMA everywhere.
//   prep (1 kernel): x->bf16 ; W* -> bf16 transposed [n][k] ; RoPE table
//   gemm_qkv (768 blk, XCD m-band swizzled): REGISTER-DIRECT core — both
//       operands' MFMA fragments are contiguous 16-B global loads (row-major
//       K-contiguous), 1-deep register prefetch, NO LDS / NO barriers in the
//       main loop (LDS-pipe was the binding resource). RoPE/V epilogues.
//   attn: causal flash attn, 256 blk x 8 waves; shfl-free softmax; raw
//         v_exp_f32; exact parity merge
//   gemm_o (256 blk, swizzled, same register-direct core): AOb@Wto -> fp32
// B=2 S=2048 D=1024 H=16 dk=64
// ---------------------------------------------------------------------------

constexpr int Bz = 2, Sq = 2048, Dm = 1024, Hh = 16, DK = 64;
constexpr int Mrows = Bz * Sq;  // 4096

typedef __attribute__((ext_vector_type(4))) float f32x4;
typedef __attribute__((ext_vector_type(2))) __bf16 bf16x2;
typedef __attribute__((ext_vector_type(4))) __bf16 bf16x4;
typedef __attribute__((ext_vector_type(8))) __bf16 bf16x8;
typedef __attribute__((ext_vector_type(8))) short short8v;

__device__ __forceinline__ f32x4 mfma16(bf16x8 a, bf16x8 b, f32x4 c) {
  return __builtin_amdgcn_mfma_f32_16x16x32_bf16(a, b, c, 0, 0, 0);
}
__device__ __forceinline__ short bfb(float x) {
  return __builtin_bit_cast(short, (__bf16)x);
}
// raw v_exp_f32 (2^x); args here are <= ~0 or large-negative -> in range
__device__ __forceinline__ float fexp2(float x) {
#if __has_builtin(__builtin_amdgcn_exp2f)
  return __builtin_amdgcn_exp2f(x);
#else
  float r;
  asm("v_exp_f32 %0, %1" : "=v"(r) : "v"(x));
  return r;
#endif
}
// async global->LDS, 16 B per lane; lds ptr must be wave-uniform
__device__ __forceinline__ void gload16(const void* g, void* l) {
  __builtin_amdgcn_global_load_lds(
      (__attribute__((address_space(1))) void*)g,
      (__attribute__((address_space(3))) void*)l, 16, 0, 0);
}

// ============================ prep (fused) =================================
// blocks [0,2048): x->bf16 ; [2048,6144): W transpose ; [6144,6400): RoPE tbl
__global__ __launch_bounds__(256) void prep_kernel(
    const float* __restrict__ x, const float* __restrict__ Wq,
    const float* __restrict__ Wk, const float* __restrict__ Wv,
    const float* __restrict__ Wo, __bf16* __restrict__ xb,
    __bf16* __restrict__ Wt, float2* __restrict__ tbl) {
  __shared__ float tile[32][33];
  const int bid = blockIdx.x, tid = threadIdx.x;
  if (bid < 2048) {
    int t = bid * 256 + tid;
    const float4* p = (const float4*)x + (size_t)t * 2;
    float4 a = p[0], b = p[1];
    bf16x8 o = {(__bf16)a.x, (__bf16)a.y, (__bf16)a.z, (__bf16)a.w,
                (__bf16)b.x, (__bf16)b.y, (__bf16)b.z, (__bf16)b.w};
    *(bf16x8*)(xb + (size_t)t * 8) = o;
  } else if (bid < 6144) {
    int wid = bid - 2048;
    int z = wid >> 10, rem = wid & 1023;
    const float* W = (z == 0) ? Wq : (z == 1) ? Wk : (z == 2) ? Wv : Wo;
    __bf16* out = Wt + (size_t)z * Dm * Dm;
    int r0 = (rem >> 5) * 32, c0 = (rem & 31) * 32;
    int r = tid >> 3, c4 = (tid & 7) * 4;
    float4 v = *(const float4*)&W[(size_t)(r0 + r) * Dm + c0 + c4];
    tile[r][c4] = v.x; tile[r][c4 + 1] = v.y;
    tile[r][c4 + 2] = v.z; tile[r][c4 + 3] = v.w;
    __syncthreads();
    int nl = tid >> 3, k4 = (tid & 7) * 4;
    bf16x4 o = {(__bf16)tile[k4][nl], (__bf16)tile[k4 + 1][nl],
                (__bf16)tile[k4 + 2][nl], (__bf16)tile[k4 + 3][nl]};
    *(bf16x4*)&out[(size_t)(c0 + nl) * Dm + r0 + k4] = o;
  } else {
    int t = (bid - 6144) * 256 + tid;  // 65536
    int s = t >> 5, j = t & 31;
    float inv = exp2f(-13.287712379549449f * (1.0f / 32.0f) * (float)j);
    float sn, cs;
    sincosf((float)s * inv, &sn, &cs);
    tbl[t] = make_float2(cs, sn);
  }
}

// ========================= bf16 MFMA GEMM core =============================
// acc[4][4] = A[m0..+128][:] @ Bt[n0..+128][:]^T. REGISTER-DIRECT: each
// wave owns a 64x64 output tile (2x2 wave grid); A/B fragments are native
// contiguous 16-B global loads (K-contiguous rows), 1-deep prefetch,
// fully-unrolled K loop with literal byte offsets. No LDS, no barriers.
__device__ __forceinline__ void gemm_core(const __bf16* __restrict__ A,
                                          const __bf16* __restrict__ Bt,
                                          f32x4 (&acc)[4][4],
                                          int m0, int n0, int tid) {
  const int lane = tid & 63, w = tid >> 6;
  const int qi = lane & 15, c = lane >> 4;
  const int wr = w >> 1, wc = w & 1;

  const __bf16* pa[4];
  const __bf16* pb[4];
#pragma unroll
  for (int i = 0; i < 4; ++i) {
    pa[i] = A + (size_t)(m0 + wr * 64 + i * 16 + qi) * Dm + c * 8;
    pb[i] = Bt + (size_t)(n0 + wc * 64 + i * 16 + qi) * Dm + c * 8;
  }

#pragma unroll
  for (int i = 0; i < 4; ++i)
#pragma unroll
    for (int j = 0; j < 4; ++j) acc[i][j] = (f32x4){0.f, 0.f, 0.f, 0.f};

  bf16x8 aC[4], bC[4], aN[4], bN[4];
#pragma unroll
  for (int i = 0; i < 4; ++i) {
    aC[i] = *(const bf16x8*)(pa[i]);
    bC[i] = *(const bf16x8*)(pb[i]);
  }
#pragma unroll
  for (int t = 0; t < 31; ++t) {
#pragma unroll
    for (int i = 0; i < 4; ++i) {
      aN[i] = *(const bf16x8*)(pa[i] + (t + 1) * 32);  // literal offsets
      bN[i] = *(const bf16x8*)(pb[i] + (t + 1) * 32);
    }
#pragma unroll
    for (int i = 0; i < 4; ++i)
#pragma unroll
      for (int j = 0; j < 4; ++j) acc[i][j] = mfma16(aC[i], bC[j], acc[i][j]);
#pragma unroll
    for (int i = 0; i < 4; ++i) {
      aC[i] = aN[i];
      bC[i] = bN[i];
    }
  }
#pragma unroll
  for (int i = 0; i < 4; ++i)
#pragma unroll
    for (int j = 0; j < 4; ++j) acc[i][j] = mfma16(aC[i], bC[j], acc[i][j]);
}

// ===================== fused QKV GEMM (flattened grid) =====================
// 768 blocks. XCD m-band swizzle: xcd=bid&7 owns m-blocks 4*xcd..+3; within
// XCD order is m-inner so B panels get back-to-back L2 reuse.
// z==0: Q + RoPE (scaled 0.125*log2e). z==1: K + RoPE. z==2: Vt[bh][d][s].
__global__ __launch_bounds__(256) void gemm_qkv(
    const __bf16* __restrict__ xb, const __bf16* __restrict__ Wt,
    const float2* __restrict__ tbl, __bf16* __restrict__ Qb,
    __bf16* __restrict__ Kb, __bf16* __restrict__ Vt) {
  __shared__ __align__(16) char smem[34816];
  const int tid = threadIdx.x;
  const int bid = blockIdx.x;
  const int xcd = bid & 7, r8 = bid >> 3;          // r8 in [0,96)
  const int mb = (xcd << 2) | (r8 & 3);            // m-block 0..31
  const int zn = r8 >> 2;                          // 0..23
  const int z = zn >> 3, nb = zn & 7;
  const int m0 = mb * 128, n0 = nb * 128;

  f32x4 acc[4][4];
  gemm_core(xb, Wt + (size_t)z * Dm * Dm, acc, m0, n0, tid);

  const int lane = tid & 63, w = tid >> 6;
  const int qi = lane & 15, c = lane >> 4;
  const int wr = w >> 1, wc = w & 1;

  if (z == 2) {  // Vt[bh][d][s]
    __syncthreads();
    short* T = (short*)smem;  // [128][136] padded
#pragma unroll
    for (int i = 0; i < 4; ++i)
#pragma unroll
      for (int j = 0; j < 4; ++j) {
        int nl = wc * 64 + j * 16 + qi;
        int mbr = wr * 64 + i * 16 + c * 4;
        bf16x4 pk = {(__bf16)acc[i][j][0], (__bf16)acc[i][j][1],
                     (__bf16)acc[i][j][2], (__bf16)acc[i][j][3]};
        *(bf16x4*)(T + nl * 136 + mbr) = pk;
      }
    __syncthreads();
    short* C = (short*)Vt;
    int b = m0 >> 11, sb = m0 & (Sq - 1);
#pragma unroll
    for (int it = 0; it < 8; ++it) {
      int f = tid + it * 256;
      int nl = f >> 4, mc = f & 15;
      short8v v = *(short8v*)(T + nl * 136 + mc * 8);
      int ng = n0 + nl;
      int d = ng & (DK - 1), h = (ng >> 6) & (Hh - 1);
      *(short8v*)(C + ((size_t)(b * Hh + h) * DK + d) * Sq + sb + mc * 8) = v;
    }
  } else {  // Q or K: stage raw bf16, RoPE on re-read (pairs in-thread)
    __syncthreads();
    short* T = (short*)smem;  // [128][136]
#pragma unroll
    for (int i = 0; i < 4; ++i)
#pragma unroll
      for (int j = 0; j < 4; ++j) {
        int nl = wc * 64 + j * 16 + qi;
        int mbr = wr * 64 + i * 16 + c * 4;
#pragma unroll
        for (int rr = 0; rr < 4; ++rr)
          T[(mbr + rr) * 136 + nl] = bfb(acc[i][j][rr]);
      }
    __syncthreads();
    const float sc = (z == 0) ? 0.18033688011112042f : 1.0f;  // 0.125*log2e
    short* C = (short*)((z == 0) ? Qb : Kb);
    const int b = m0 >> 11;
#pragma unroll
    for (int it = 0; it < 8; ++it) {
      int f = tid + it * 256;
      int ml = f >> 4, c16 = f & 15;
      bf16x8 v = *(bf16x8*)(T + ml * 136 + c16 * 8);
      int s = (m0 + ml) & (Sq - 1);
      int n = n0 + c16 * 8;
      int d0 = n & (DK - 1), h = (n >> 6) & (Hh - 1);
      int jj = d0 >> 1;
      float4 t01 = *(const float4*)&tbl[s * 32 + jj];      // cos0,sin0,cos1,sin1
      float4 t23 = *(const float4*)&tbl[s * 32 + jj + 2];
      bf16x8 o;
      float x0 = (float)v[0], y0 = (float)v[1];
      o[0] = (__bf16)((x0 * t01.x - y0 * t01.y) * sc);
      o[1] = (__bf16)((y0 * t01.x + x0 * t01.y) * sc);
      float x1 = (float)v[2], y1 = (float)v[3];
      o[2] = (__bf16)((x1 * t01.z - y1 * t01.w) * sc);
      o[3] = (__bf16)((y1 * t01.z + x1 * t01.w) * sc);
      float x2 = (float)v[4], y2 = (float)v[5];
      o[4] = (__bf16)((x2 * t23.x - y2 * t23.y) * sc);
      o[5] = (__bf16)((y2 * t23.x + x2 * t23.y) * sc);
      float x3 = (float)v[6], y3 = (float)v[7];
      o[6] = (__bf16)((x3 * t23.z - y3 * t23.w) * sc);
      o[7] = (__bf16)((y3 * t23.z + x3 * t23.w) * sc);
      *(bf16x8*)(C + ((size_t)(b * Hh + h) * Sq + s) * DK + d0) = o;
    }
  }
}

// ============================== O GEMM =====================================
// 256 blocks, XCD m-band swizzle. fp32 output via 2-pass LDS transpose.
__global__ __launch_bounds__(256) void gemm_o(
    const __bf16* __restrict__ AOb, const __bf16* __restrict__ Wto,
    float* __restrict__ C) {
  __shared__ __align__(16) char smem[33792];
  const int tid = threadIdx.x;
  const int bid = blockIdx.x;
  const int xcd = bid & 7, r8 = bid >> 3;          // r8 in [0,32)
  const int mb = (xcd << 2) | (r8 & 3);
  const int nb = r8 >> 2;
  const int m0 = mb * 128, n0 = nb * 128;

  f32x4 acc[4][4];
  gemm_core(AOb, Wto, acc, m0, n0, tid);

  const int lane = tid & 63, w = tid >> 6;
  const int qi = lane & 15, c = lane >> 4;
  const int wr = w >> 1, wc = w & 1;
  float* T32 = (float*)smem;  // [64][132] = 33792 B

#pragma unroll
  for (int pass = 0; pass < 2; ++pass) {
    __syncthreads();
#pragma unroll
    for (int i2 = 0; i2 < 2; ++i2) {
      int i = pass * 2 + i2;
#pragma unroll
      for (int j = 0; j < 4; ++j) {
        int nl = wc * 64 + j * 16 + qi;
        int cm = wr * 32 + i2 * 16 + c * 4;
#pragma unroll
        for (int rr = 0; rr < 4; ++rr)
          T32[(cm + rr) * 132 + nl] = acc[i][j][rr];
      }
    }
    __syncthreads();
#pragma unroll
    for (int it = 0; it < 8; ++it) {
      int f = tid + it * 256;           // 0..2047
      int cm = f >> 5, c4 = f & 31;
      float4 v = *(float4*)(T32 + cm * 132 + c4 * 4);
      int m = m0 + (cm >> 5) * 64 + pass * 32 + (cm & 31);
      *(float4*)&C[(size_t)m * Dm + n0 + c4 * 4] = v;
    }
  }
}

// ======================= Flash attention (bf16 MFMA) ========================
// 256 blocks x 8 waves (512 thr). wave -> (cg, rg, par); 32 q-rows per wave.
// m-group m: chunks 2m/2m+1, both need m+1 staged 128-k tiles; serial
// m-groups (15-j, j) -> uniform 17 intervals. SHFL-FREE common path:
// per-lane deferred-max check; l_ = per-lane PARTIAL row-sum reduced once
// at merge; raw v_exp_f32. Exact parity merge per m-group. XCD-partitioned.
// LDS (96 KB): K[2][16K], V[2][16K], P[8][4K]. 1 block/CU, grid 256.
__global__ __launch_bounds__(512, 2) void attn_kernel(
    const __bf16* __restrict__ Qb, const __bf16* __restrict__ Kb,
    const __bf16* __restrict__ Vt, __bf16* __restrict__ AOb) {
  extern __shared__ __align__(16) char smem[];

  const int bid = blockIdx.x;            // 256
  const int xcd = bid & 7;               // hw round-robin -> XCD id (heuristic)
  const int idx = bid >> 3;              // 0..31 within XCD
  const int bh = (xcd << 2) | (idx >> 3);
  const int j8 = idx & 7;                // m-groups: 15-j8 then j8
  const int b = bh >> 4, h = bh & (Hh - 1);
  const int tid = threadIdx.x, lane = tid & 63, w = tid >> 6;  // w 0..7
  const int cg = w & 1, rg = (w >> 1) & 1, par = w >> 2;
  const int g = lane >> 4, qi = lane & 15;

  const __bf16* Qp = Qb + (size_t)bh * Sq * DK;
  const __bf16* Kp = Kb + (size_t)bh * Sq * DK;
  const __bf16* Vp = Vt + (size_t)bh * DK * Sq;

  char* myP = smem + 65536 + w * 4096;   // [2 i][16 rows][128 B]
  const int swz = (qi & 7) << 4;
  const int srow8 = lane >> 3, scol8 = lane & 7;
  const int srow4 = lane >> 4, scol16 = lane & 15;
  short* AOs = (short*)AOb;

  // stage K[128][64] + V[64][128] of 128-k tile t into buffer cb
  auto stage = [&](int cb, int t) {
    const int kbase = t * 128;
    char* Kd = smem + cb * 16384;
    char* Vd = smem + 32768 + cb * 16384;
#pragma unroll
    for (int s2 = 0; s2 < 2; ++s2) {
      int seg = w * 2 + s2;
      int r = seg * 8 + srow8;                       // K row 0..127
      gload16(Kp + (size_t)(kbase + r) * DK + ((scol8 ^ (r & 7)) << 3),
              Kd + seg * 1024);
      int d = seg * 4 + srow4;                       // V row 0..63
      int ss = (scol16 & 8) | ((scol16 ^ (d & 7)) & 7);  // keep k-half bit
      gload16(Vp + (size_t)d * Sq + kbase + ss * 8, Vd + seg * 1024);
    }
  };

  // one interval: this wave's 64-k parity half x its 32 q-rows
  auto tile = [&](int cb, bool domask, int kbase, int q0w,
                  const bf16x8 (&qf)[2][2], f32x4 (&acc)[2][4],
                  float (&m_)[2], float (&l_)[2]) {
    const char* Kt = smem + cb * 16384 + par * 8192;
    const char* Vv = smem + 32768 + cb * 16384;
    const int vpo = par * 128;

    bf16x8 kf[4][2];
#pragma unroll
    for (int bb = 0; bb < 4; ++bb) {
      int rr = 16 * bb + qi;
      kf[bb][0] = *(const bf16x8*)(Kt + rr * 128 + ((g ^ (rr & 7)) << 4));
      kf[bb][1] = *(const bf16x8*)(Kt + rr * 128 + (((g + 4) ^ (rr & 7)) << 4));
    }
    bf16x8 vf[4][2];
#pragma unroll
    for (int j = 0; j < 4; ++j) {
      int rr = 16 * j + qi;
      vf[j][0] = *(const bf16x8*)(Vv + rr * 256 + vpo + ((g ^ (rr & 7)) << 4));
      vf[j][1] =
          *(const bf16x8*)(Vv + rr * 256 + vpo + (((g + 4) ^ (rr & 7)) << 4));
    }

    // ---- QK^T for BOTH 16-row groups (group1 overlaps group0 softmax) ----
    f32x4 st[2][4];
    __builtin_amdgcn_s_setprio(1);
#pragma unroll
    for (int i = 0; i < 2; ++i)
#pragma unroll
      for (int bb = 0; bb < 4; ++bb) {
        st[i][bb] = mfma16(kf[bb][0], qf[i][0], (f32x4){0.f, 0.f, 0.f, 0.f});
        st[i][bb] = mfma16(kf[bb][1], qf[i][1], st[i][bb]);
      }
    __builtin_amdgcn_s_setprio(0);

    if (domask) {
#pragma unroll
      for (int i = 0; i < 2; ++i)
#pragma unroll
        for (int bb = 0; bb < 4; ++bb)
#pragma unroll
          for (int r = 0; r < 4; ++r)
            if (kbase + 16 * bb + 4 * g + r > q0w + i * 16 + qi)
              st[i][bb][r] = -1e30f;
    }

#pragma unroll
    for (int i = 0; i < 2; ++i) {
      // per-lane partial max (tree, in-register only)
      float mb4[4];
#pragma unroll
      for (int bb = 0; bb < 4; ++bb)
        mb4[bb] = fmaxf(fmaxf(st[i][bb][0], st[i][bb][1]),
                        fmaxf(st[i][bb][2], st[i][bb][3]));
      float tpart = fmaxf(fmaxf(mb4[0], mb4[1]), fmaxf(mb4[2], mb4[3]));

      // shfl-free deferred check: rescale only if some lane's partial max
      // exceeds m_+7 (then do the full cross-lane reduction, exact).
      if (!__all(tpart <= m_[i] + 7.0f)) {
        float tmax = tpart;
        tmax = fmaxf(tmax, __shfl_xor(tmax, 16));
        tmax = fmaxf(tmax, __shfl_xor(tmax, 32));
        const float mnew = fmaxf(m_[i], tmax);
        const float corr = fexp2(m_[i] - mnew);
        l_[i] *= corr;
        float cr[4];
#pragma unroll
        for (int r = 0; r < 4; ++r) cr[r] = __shfl(corr, 4 * g + r);
#pragma unroll
        for (int j = 0; j < 4; ++j) {
          acc[i][j][0] *= cr[0]; acc[i][j][1] *= cr[1];
          acc[i][j][2] *= cr[2]; acc[i][j][3] *= cr[3];
        }
        m_[i] = mnew;
      }

      // exp2 + pack + P -> LDS ; l_ accumulates PARTIAL (no shfl)
      char* Pi = myP + i * 2048;
      float lsb[4];
#pragma unroll
      for (int bb = 0; bb < 4; ++bb) {
        float p0 = fexp2(st[i][bb][0] - m_[i]), p1 = fexp2(st[i][bb][1] - m_[i]);
        float p2 = fexp2(st[i][bb][2] - m_[i]), p3 = fexp2(st[i][bb][3] - m_[i]);
        lsb[bb] = (p0 + p1) + (p2 + p3);
        bf16x2 w0 = {(__bf16)p0, (__bf16)p1};
        bf16x2 w1 = {(__bf16)p2, (__bf16)p3};
        *(uint2*)(Pi + qi * 128 + ((32 * bb + 8 * g) ^ swz)) =
            make_uint2(__builtin_bit_cast(unsigned int, w0),
                       __builtin_bit_cast(unsigned int, w1));
      }
      l_[i] += (lsb[0] + lsb[1]) + (lsb[2] + lsb[3]);

      bf16x8 pa0 = *(bf16x8*)(Pi + qi * 128 + ((16 * g) ^ swz));
      bf16x8 pa1 = *(bf16x8*)(Pi + qi * 128 + ((64 + 16 * g) ^ swz));
      __builtin_amdgcn_s_setprio(1);
#pragma unroll
      for (int j = 0; j < 4; ++j) {
        acc[i][j] = mfma16(pa0, vf[j][0], acc[i][j]);
        acc[i][j] = mfma16(pa1, vf[j][1], acc[i][j]);
      }
      __builtin_amdgcn_s_setprio(0);
    }
  };

  auto run_mgroup = [&](int m) {
    const int q0w = 128 * m + cg * 64 + rg * 32;  // this wave's 32 rows

    bf16x8 qf[2][2];
#pragma unroll
    for (int i = 0; i < 2; ++i) {
      qf[i][0] = *(const bf16x8*)(Qp + (q0w + i * 16 + qi) * DK + 8 * g);
      qf[i][1] = *(const bf16x8*)(Qp + (q0w + i * 16 + qi) * DK + 32 + 8 * g);
    }
    f32x4 acc[2][4];
#pragma unroll
    for (int i = 0; i < 2; ++i)
#pragma unroll
      for (int j = 0; j < 4; ++j) acc[i][j] = (f32x4){0.f, 0.f, 0.f, 0.f};
    float m_[2] = {-1e30f, -1e30f}, l_[2] = {0.f, 0.f};  // l_ = lane PARTIAL

    __syncthreads();  // protect LDS from previous m-group's readers
    stage(0, 0);

    int cur = 0;
    for (int t = 0; t < m; ++t) {  // full intervals: no mask, no skip
      __syncthreads();             // buf[cur] staged
      stage(cur ^ 1, t + 1);
      tile(cur, false, 0, q0w, qf, acc, m_, l_);
      cur ^= 1;
    }
    __syncthreads();
    // final tile t=m: ktv = 2m+par vs qc = 2m+cg
    if (!(par == 1 && cg == 0))
      tile(cur, par == cg, (2 * m + par) * 64, q0w, qf, acc, m_, l_);

    // ---- exact merge of parity states (through free K/V LDS) ----
    __syncthreads();
    char* Mb = smem + (cg * 2 + rg) * 9216 + lane * 144;
    if (par == 1) {
#pragma unroll
      for (int i = 0; i < 2; ++i)
#pragma unroll
        for (int j = 0; j < 4; ++j)
          *(f32x4*)(Mb + (i * 4 + j) * 16) = acc[i][j];
      *(float*)(Mb + 128) = m_[0];
      *(float*)(Mb + 132) = m_[1];
      *(float*)(Mb + 136) = l_[0];
      *(float*)(Mb + 140) = l_[1];
    }
    __syncthreads();
    if (par == 0) {
#pragma unroll
      for (int i = 0; i < 2; ++i) {
        float m1 = *(const float*)(Mb + 128 + i * 4);
        float l1 = *(const float*)(Mb + 136 + i * 4);
        const float mn = fmaxf(m_[i], m1);
        const float c0 = fexp2(m_[i] - mn), c1 = fexp2(m1 - mn);
        float lt = l_[i] * c0 + l1 * c1;      // per-lane partial
        lt += __shfl_xor(lt, 16);             // reduce across g once
        lt += __shfl_xor(lt, 32);
        float cr0[4], cr1[4], ir[4];
        const float inv = 1.f / lt;
#pragma unroll
        for (int r = 0; r < 4; ++r) {
          cr0[r] = __shfl(c0, 4 * g + r);
          cr1[r] = __shfl(c1, 4 * g + r);
          ir[r] = __shfl(inv, 4 * g + r);
        }
#pragma unroll
        for (int j = 0; j < 4; ++j) {
          f32x4 a1 = *(const f32x4*)(Mb + (i * 4 + j) * 16);
#pragma unroll
          for (int r = 0; r < 4; ++r) {
            float v = acc[i][j][r] * cr0[r] + a1[r] * cr1[r];
            AOs[((size_t)b * Sq + q0w + i * 16 + 4 * g + r) * Dm + h * DK +
                16 * j + qi] = bfb(v * ir[r]);
          }
        }
      }
    }
  };

  run_mgroup(15 - j8);  // big m-group first
  run_mgroup(j8);
}

// ================================ launch ===================================
extern "C" void kernel_launch(void* const* d_in, const int* in_sizes, int n_in,
                              void* d_out, int out_size, void* d_ws,
                              size_t ws_size, hipStream_t stream) {
  const float* x  = (const float*)d_in[0];
  const float* Wq = (const float*)d_in[1];
  const float* Wk = (const float*)d_in[2];
  const float* Wv = (const float*)d_in[3];
  const float* Wo = (const float*)d_in[4];
  float* out = (float*)d_out;

  char* w = (char*)d_ws;
  __bf16* Qb  = (__bf16*)(w);                 // 8 MB [bh][s][64] (pre-scaled)
  __bf16* Kb  = (__bf16*)(w + (8u << 20));    // 8 MB
  __bf16* Vt  = (__bf16*)(w + (16u << 20));   // 8 MB [bh][64][s]
  __bf16* AOb = (__bf16*)(w + (24u << 20));   // 8 MB [B,S,D]
  __bf16* xb  = (__bf16*)(w + (32u << 20));   // 8 MB [4096][1024]
  __bf16* Wt  = (__bf16*)(w + (40u << 20));   // 4 x 2 MB [n][k]
  float2* tbl = (float2*)(w + (48u << 20));   // 512 KB

  prep_kernel<<<6400, 256, 0, stream>>>(x, Wq, Wk, Wv, Wo, xb, Wt, tbl);
  gemm_qkv<<<768, 256, 0, stream>>>(xb, Wt, tbl, Qb, Kb, Vt);
  attn_kernel<<<256, 512, 98304, stream>>>(Qb, Kb, Vt, AOb);
  gemm_o<<<256, 256, 0, stream>>>(AOb, Wt + (size_t)3 * Dm * Dm, out);
}

// Round 21
// 95.752 us; speedup vs baseline: 1.7778x; 1.7778x over previous
//
#include <hip/hip_runtime.h>
#include <cmath>

// ---------------------------------------------------------------------------
// MHA forward, bf16-MFMA everywhere.
//   prep (1 kernel): x->bf16 ; W* -> bf16 transposed [n][k] ; RoPE table
//   gemm_qkv (768 blk, XCD m-band swizzled): BK=32, triple-buffered pipeline,
//       counted s_waitcnt vmcnt(4) + raw s_barrier (round-19 core)
//   attn: causal flash attn, 256 blk x 8 waves; 3-buffer 2-in-flight K/V
//       pipeline (counted vmcnt, raw barrier); shfl-free softmax; raw
//       v_exp_f32; exact parity merge
//   gemm_o (256 blk, swizzled, same pipelined core): AOb@Wto -> out fp32
// B=2 S=2048 D=1024 H=16 dk=64
// ---------------------------------------------------------------------------

constexpr int Bz = 2, Sq = 2048, Dm = 1024, Hh = 16, DK = 64;
constexpr int Mrows = Bz * Sq;  // 4096

typedef __attribute__((ext_vector_type(4))) float f32x4;
typedef __attribute__((ext_vector_type(2))) __bf16 bf16x2;
typedef __attribute__((ext_vector_type(4))) __bf16 bf16x4;
typedef __attribute__((ext_vector_type(8))) __bf16 bf16x8;
typedef __attribute__((ext_vector_type(8))) short short8v;

__device__ __forceinline__ f32x4 mfma16(bf16x8 a, bf16x8 b, f32x4 c) {
  return __builtin_amdgcn_mfma_f32_16x16x32_bf16(a, b, c, 0, 0, 0);
}
__device__ __forceinline__ short bfb(float x) {
  return __builtin_bit_cast(short, (__bf16)x);
}
// raw v_exp_f32 (2^x); args here are <= ~0 or large-negative -> in range
__device__ __forceinline__ float fexp2(float x) {
#if __has_builtin(__builtin_amdgcn_exp2f)
  return __builtin_amdgcn_exp2f(x);
#else
  float r;
  asm("v_exp_f32 %0, %1" : "=v"(r) : "v"(x));
  return r;
#endif
}
// async global->LDS, 16 B per lane; lds ptr must be wave-uniform
__device__ __forceinline__ void gload16(const void* g, void* l) {
  __builtin_amdgcn_global_load_lds(
      (__attribute__((address_space(1))) void*)g,
      (__attribute__((address_space(3))) void*)l, 16, 0, 0);
}

// ============================ prep (fused) =================================
// blocks [0,2048): x->bf16 ; [2048,6144): W transpose ; [6144,6400): RoPE tbl
__global__ __launch_bounds__(256) void prep_kernel(
    const float* __restrict__ x, const float* __restrict__ Wq,
    const float* __restrict__ Wk, const float* __restrict__ Wv,
    const float* __restrict__ Wo, __bf16* __restrict__ xb,
    __bf16* __restrict__ Wt, float2* __restrict__ tbl) {
  __shared__ float tile[32][33];
  const int bid = blockIdx.x, tid = threadIdx.x;
  if (bid < 2048) {
    int t = bid * 256 + tid;
    const float4* p = (const float4*)x + (size_t)t * 2;
    float4 a = p[0], b = p[1];
    bf16x8 o = {(__bf16)a.x, (__bf16)a.y, (__bf16)a.z, (__bf16)a.w,
                (__bf16)b.x, (__bf16)b.y, (__bf16)b.z, (__bf16)b.w};
    *(bf16x8*)(xb + (size_t)t * 8) = o;
  } else if (bid < 6144) {
    int wid = bid - 2048;
    int z = wid >> 10, rem = wid & 1023;
    const float* W = (z == 0) ? Wq : (z == 1) ? Wk : (z == 2) ? Wv : Wo;
    __bf16* out = Wt + (size_t)z * Dm * Dm;
    int r0 = (rem >> 5) * 32, c0 = (rem & 31) * 32;
    int r = tid >> 3, c4 = (tid & 7) * 4;
    float4 v = *(const float4*)&W[(size_t)(r0 + r) * Dm + c0 + c4];
    tile[r][c4] = v.x; tile[r][c4 + 1] = v.y;
    tile[r][c4 + 2] = v.z; tile[r][c4 + 3] = v.w;
    __syncthreads();
    int nl = tid >> 3, k4 = (tid & 7) * 4;
    bf16x4 o = {(__bf16)tile[k4][nl], (__bf16)tile[k4 + 1][nl],
                (__bf16)tile[k4 + 2][nl], (__bf16)tile[k4 + 3][nl]};
    *(bf16x4*)&out[(size_t)(c0 + nl) * Dm + r0 + k4] = o;
  } else {
    int t = (bid - 6144) * 256 + tid;  // 65536
    int s = t >> 5, j = t & 31;
    float inv = exp2f(-13.287712379549449f * (1.0f / 32.0f) * (float)j);
    float sn, cs;
    sincosf((float)s * inv, &sn, &cs);
    tbl[t] = make_float2(cs, sn);
  }
}

// ========================= bf16 MFMA GEMM core =============================
// acc[4][4] = A[m0..+128][:] @ Bt[n0..+128][:]^T. BK=32, TRIPLE-buffered.
// Per interval: s_waitcnt vmcnt(4) (tile t's loads done; t+1 stays in
// flight) -> s_barrier -> issue stage(t+2) -> compute tile t. The vmcnt(0)
// drain happens only for the final tile. LDS: As[3][128][32] @0 (24 KB),
// Bs[3][128][32] @24K (24 KB) = 48 KB.
__device__ __forceinline__ void gemm_core(const __bf16* __restrict__ A,
                                          const __bf16* __restrict__ Bt,
                                          char* smem, f32x4 (&acc)[4][4],
                                          int m0, int n0, int tid) {
  short* As = (short*)smem;             // [3][128][32]
  short* Bs = (short*)(smem + 24576);   // [3][128][32]
  const int lane = tid & 63, w = tid >> 6;
  const int qi = lane & 15, c = lane >> 4;
  const int wr = w >> 1, wc = w & 1;
  const int srow = lane >> 2;                        // 0..15
  const int scol = (((lane & 3) ^ (srow & 3)) * 8);  // swizzled SOURCE col
  const __bf16* gA = A + (size_t)(m0 + w * 16 + srow) * Dm + scol;
  const __bf16* gB = Bt + (size_t)(n0 + w * 16 + srow) * Dm + scol;
  short* lA = As + w * 512;  // wave-uniform LDS dest (buffer 0 slot)
  short* lB = Bs + w * 512;
  const int cx = (c ^ (qi & 3)) * 8;  // swizzled read col (row&3 == qi&3)

  auto stage = [&](int cb, int k0) {
    gload16(gA + k0, lA + cb * 4096);
    gload16(gA + (size_t)64 * Dm + k0, lA + cb * 4096 + 2048);
    gload16(gB + k0, lB + cb * 4096);
    gload16(gB + (size_t)64 * Dm + k0, lB + cb * 4096 + 2048);
  };
  auto compute = [&](int cb) {
    bf16x8 af[4], bfv[4];
#pragma unroll
    for (int i = 0; i < 4; ++i) {
      af[i]  = *(bf16x8*)(As + cb * 4096 + (wr * 64 + i * 16 + qi) * 32 + cx);
      bfv[i] = *(bf16x8*)(Bs + cb * 4096 + (wc * 64 + i * 16 + qi) * 32 + cx);
    }
#pragma unroll
    for (int i = 0; i < 4; ++i)
#pragma unroll
      for (int j = 0; j < 4; ++j) acc[i][j] = mfma16(af[i], bfv[j], acc[i][j]);
  };

#pragma unroll
  for (int i = 0; i < 4; ++i)
#pragma unroll
    for (int j = 0; j < 4; ++j) acc[i][j] = (f32x4){0.f, 0.f, 0.f, 0.f};

  stage(0, 0);
  stage(1, 32);
  int cur = 0;
  for (int k0 = 0; k0 < Dm - 32; k0 += 32) {
    asm volatile("s_waitcnt vmcnt(4)" ::: "memory");  // tile t staged
    __builtin_amdgcn_s_barrier();                     // ...on all waves
    if (k0 + 64 < Dm) {
      int nx = cur + 2;
      if (nx >= 3) nx -= 3;
      stage(nx, k0 + 64);  // into buffer freed at iter t-1; stays in flight
    }
    compute(cur);
    if (++cur == 3) cur = 0;
  }
  asm volatile("s_waitcnt vmcnt(0)" ::: "memory");  // final tile
  __builtin_amdgcn_s_barrier();
  compute(cur);
}

// ===================== fused QKV GEMM (flattened grid) =====================
// 768 blocks. XCD m-band swizzle: xcd=bid&7 owns m-blocks 4*xcd..+3; within
// XCD order is m-inner so B tiles get back-to-back L2 reuse.
// z==0: Q + RoPE (scaled 0.125*log2e). z==1: K + RoPE. z==2: Vt[bh][d][s].
__global__ __launch_bounds__(256) void gemm_qkv(
    const __bf16* __restrict__ xb, const __bf16* __restrict__ Wt,
    const float2* __restrict__ tbl, __bf16* __restrict__ Qb,
    __bf16* __restrict__ Kb, __bf16* __restrict__ Vt) {
  __shared__ __align__(16) char smem[49152];
  const int tid = threadIdx.x;
  const int bid = blockIdx.x;
  const int xcd = bid & 7, r8 = bid >> 3;          // r8 in [0,96)
  const int mb = (xcd << 2) | (r8 & 3);            // m-block 0..31
  const int zn = r8 >> 2;                          // 0..23
  const int z = zn >> 3, nb = zn & 7;
  const int m0 = mb * 128, n0 = nb * 128;

  f32x4 acc[4][4];
  gemm_core(xb, Wt + (size_t)z * Dm * Dm, smem, acc, m0, n0, tid);

  const int lane = tid & 63, w = tid >> 6;
  const int qi = lane & 15, c = lane >> 4;
  const int wr = w >> 1, wc = w & 1;

  if (z == 2) {  // Vt[bh][d][s]
    __syncthreads();
    short* T = (short*)smem;  // [128][136] padded
#pragma unroll
    for (int i = 0; i < 4; ++i)
#pragma unroll
      for (int j = 0; j < 4; ++j) {
        int nl = wc * 64 + j * 16 + qi;
        int mbr = wr * 64 + i * 16 + c * 4;
        bf16x4 pk = {(__bf16)acc[i][j][0], (__bf16)acc[i][j][1],
                     (__bf16)acc[i][j][2], (__bf16)acc[i][j][3]};
        *(bf16x4*)(T + nl * 136 + mbr) = pk;
      }
    __syncthreads();
    short* C = (short*)Vt;
    int b = m0 >> 11, sb = m0 & (Sq - 1);
#pragma unroll
    for (int it = 0; it < 8; ++it) {
      int f = tid + it * 256;
      int nl = f >> 4, mc = f & 15;
      short8v v = *(short8v*)(T + nl * 136 + mc * 8);
      int ng = n0 + nl;
      int d = ng & (DK - 1), h = (ng >> 6) & (Hh - 1);
      *(short8v*)(C + ((size_t)(b * Hh + h) * DK + d) * Sq + sb + mc * 8) = v;
    }
  } else {  // Q or K: stage raw bf16, RoPE on re-read (pairs in-thread)
    __syncthreads();
    short* T = (short*)smem;  // [128][136]
#pragma unroll
    for (int i = 0; i < 4; ++i)
#pragma unroll
      for (int j = 0; j < 4; ++j) {
        int nl = wc * 64 + j * 16 + qi;
        int mbr = wr * 64 + i * 16 + c * 4;
#pragma unroll
        for (int rr = 0; rr < 4; ++rr)
          T[(mbr + rr) * 136 + nl] = bfb(acc[i][j][rr]);
      }
    __syncthreads();
    const float sc = (z == 0) ? 0.18033688011112042f : 1.0f;  // 0.125*log2e
    short* C = (short*)((z == 0) ? Qb : Kb);
    const int b = m0 >> 11;
#pragma unroll
    for (int it = 0; it < 8; ++it) {
      int f = tid + it * 256;
      int ml = f >> 4, c16 = f & 15;
      bf16x8 v = *(bf16x8*)(T + ml * 136 + c16 * 8);
      int s = (m0 + ml) & (Sq - 1);
      int n = n0 + c16 * 8;
      int d0 = n & (DK - 1), h = (n >> 6) & (Hh - 1);
      int jj = d0 >> 1;
      float4 t01 = *(const float4*)&tbl[s * 32 + jj];      // cos0,sin0,cos1,sin1
      float4 t23 = *(const float4*)&tbl[s * 32 + jj + 2];
      bf16x8 o;
      float x0 = (float)v[0], y0 = (float)v[1];
      o[0] = (__bf16)((x0 * t01.x - y0 * t01.y) * sc);
      o[1] = (__bf16)((y0 * t01.x + x0 * t01.y) * sc);
      float x1 = (float)v[2], y1 = (float)v[3];
      o[2] = (__bf16)((x1 * t01.z - y1 * t01.w) * sc);
      o[3] = (__bf16)((y1 * t01.z + x1 * t01.w) * sc);
      float x2 = (float)v[4], y2 = (float)v[5];
      o[4] = (__bf16)((x2 * t23.x - y2 * t23.y) * sc);
      o[5] = (__bf16)((y2 * t23.x + x2 * t23.y) * sc);
      float x3 = (float)v[6], y3 = (float)v[7];
      o[6] = (__bf16)((x3 * t23.z - y3 * t23.w) * sc);
      o[7] = (__bf16)((y3 * t23.z + x3 * t23.w) * sc);
      *(bf16x8*)(C + ((size_t)(b * Hh + h) * Sq + s) * DK + d0) = o;
    }
  }
}

// ============================== O GEMM =====================================
// 256 blocks, XCD m-band swizzle. fp32 output via 2-pass LDS transpose.
__global__ __launch_bounds__(256) void gemm_o(
    const __bf16* __restrict__ AOb, const __bf16* __restrict__ Wto,
    float* __restrict__ C) {
  __shared__ __align__(16) char smem[49152];
  const int tid = threadIdx.x;
  const int bid = blockIdx.x;
  const int xcd = bid & 7, r8 = bid >> 3;          // r8 in [0,32)
  const int mb = (xcd << 2) | (r8 & 3);
  const int nb = r8 >> 2;
  const int m0 = mb * 128, n0 = nb * 128;

  f32x4 acc[4][4];
  gemm_core(AOb, Wto, smem, acc, m0, n0, tid);

  const int lane = tid & 63, w = tid >> 6;
  const int qi = lane & 15, c = lane >> 4;
  const int wr = w >> 1, wc = w & 1;
  float* T32 = (float*)smem;  // [64][132] = 33792 B

#pragma unroll
  for (int pass = 0; pass < 2; ++pass) {
    __syncthreads();
#pragma unroll
    for (int i2 = 0; i2 < 2; ++i2) {
      int i = pass * 2 + i2;
#pragma unroll
      for (int j = 0; j < 4; ++j) {
        int nl = wc * 64 + j * 16 + qi;
        int cm = wr * 32 + i2 * 16 + c * 4;
#pragma unroll
        for (int rr = 0; rr < 4; ++rr)
          T32[(cm + rr) * 132 + nl] = acc[i][j][rr];
      }
    }
    __syncthreads();
#pragma unroll
    for (int it = 0; it < 8; ++it) {
      int f = tid + it * 256;           // 0..2047
      int cm = f >> 5, c4 = f & 31;
      float4 v = *(float4*)(T32 + cm * 132 + c4 * 4);
      int m = m0 + (cm >> 5) * 64 + pass * 32 + (cm & 31);
      *(float4*)&C[(size_t)m * Dm + n0 + c4 * 4] = v;
    }
  }
}

// ======================= Flash attention (bf16 MFMA) ========================
// 256 blocks x 8 waves (512 thr). wave -> (cg, rg, par); 32 q-rows per wave.
// m-group m: chunks 2m/2m+1, serial m-groups (15-j, j) -> uniform 17
// intervals. 3-BUFFER K/V pipeline, 2 tiles in flight, counted
// s_waitcnt vmcnt(4) + raw s_barrier (vmcnt(0) only on final tile).
// SHFL-FREE softmax common path; per-lane deferred-max; l_ partial row-sum
// reduced once at merge; raw v_exp_f32. Exact parity merge. XCD-partitioned.
// LDS (128 KB): K[3][16K]@0, V[3][16K]@48K, P[8][4K]@96K. 1 block/CU.
__global__ __launch_bounds__(512, 2) void attn_kernel(
    const __bf16* __restrict__ Qb, const __bf16* __restrict__ Kb,
    const __bf16* __restrict__ Vt, __bf16* __restrict__ AOb) {
  extern __shared__ __align__(16) char smem[];

  const int bid = blockIdx.x;            // 256
  const int xcd = bid & 7;               // hw round-robin -> XCD id (heuristic)
  const int idx = bid >> 3;              // 0..31 within XCD
  const int bh = (xcd << 2) | (idx >> 3);
  const int j8 = idx & 7;                // m-groups: 15-j8 then j8
  const int b = bh >> 4, h = bh & (Hh - 1);
  const int tid = threadIdx.x, lane = tid & 63, w = tid >> 6;  // w 0..7
  const int cg = w & 1, rg = (w >> 1) & 1, par = w >> 2;
  const int g = lane >> 4, qi = lane & 15;

  const __bf16* Qp = Qb + (size_t)bh * Sq * DK;
  const __bf16* Kp = Kb + (size_t)bh * Sq * DK;
  const __bf16* Vp = Vt + (size_t)bh * DK * Sq;

  char* myP = smem + 98304 + w * 4096;   // [2 i][16 rows][128 B]
  const int swz = (qi & 7) << 4;
  const int srow8 = lane >> 3, scol8 = lane & 7;
  const int srow4 = lane >> 4, scol16 = lane & 15;
  short* AOs = (short*)AOb;

  // stage K[128][64] + V[64][128] of 128-k tile t into buffer cb (4 loads/wave)
  auto stage = [&](int cb, int t) {
    const int kbase = t * 128;
    char* Kd = smem + cb * 16384;
    char* Vd = smem + 49152 + cb * 16384;
#pragma unroll
    for (int s2 = 0; s2 < 2; ++s2) {
      int seg = w * 2 + s2;
      int r = seg * 8 + srow8;                       // K row 0..127
      gload16(Kp + (size_t)(kbase + r) * DK + ((scol8 ^ (r & 7)) << 3),
              Kd + seg * 1024);
      int d = seg * 4 + srow4;                       // V row 0..63
      int ss = (scol16 & 8) | ((scol16 ^ (d & 7)) & 7);  // keep k-half bit
      gload16(Vp + (size_t)d * Sq + kbase + ss * 8, Vd + seg * 1024);
    }
  };

  // one interval: this wave's 64-k parity half x its 32 q-rows
  auto tile = [&](int cb, bool domask, int kbase, int q0w,
                  const bf16x8 (&qf)[2][2], f32x4 (&acc)[2][4],
                  float (&m_)[2], float (&l_)[2]) {
    const char* Kt = smem + cb * 16384 + par * 8192;
    const char* Vv = smem + 49152 + cb * 16384;
    const int vpo = par * 128;

    bf16x8 kf[4][2];
#pragma unroll
    for (int bb = 0; bb < 4; ++bb) {
      int rr = 16 * bb + qi;
      kf[bb][0] = *(const bf16x8*)(Kt + rr * 128 + ((g ^ (rr & 7)) << 4));
      kf[bb][1] = *(const bf16x8*)(Kt + rr * 128 + (((g + 4) ^ (rr & 7)) << 4));
    }
    bf16x8 vf[4][2];
#pragma unroll
    for (int j = 0; j < 4; ++j) {
      int rr = 16 * j + qi;
      vf[j][0] = *(const bf16x8*)(Vv + rr * 256 + vpo + ((g ^ (rr & 7)) << 4));
      vf[j][1] =
          *(const bf16x8*)(Vv + rr * 256 + vpo + (((g + 4) ^ (rr & 7)) << 4));
    }

    // ---- QK^T for BOTH 16-row groups (group1 overlaps group0 softmax) ----
    f32x4 st[2][4];
    __builtin_amdgcn_s_setprio(1);
#pragma unroll
    for (int i = 0; i < 2; ++i)
#pragma unroll
      for (int bb = 0; bb < 4; ++bb) {
        st[i][bb] = mfma16(kf[bb][0], qf[i][0], (f32x4){0.f, 0.f, 0.f, 0.f});
        st[i][bb] = mfma16(kf[bb][1], qf[i][1], st[i][bb]);
      }
    __builtin_amdgcn_s_setprio(0);

    if (domask) {
#pragma unroll
      for (int i = 0; i < 2; ++i)
#pragma unroll
        for (int bb = 0; bb < 4; ++bb)
#pragma unroll
          for (int r = 0; r < 4; ++r)
            if (kbase + 16 * bb + 4 * g + r > q0w + i * 16 + qi)
              st[i][bb][r] = -1e30f;
    }

#pragma unroll
    for (int i = 0; i < 2; ++i) {
      // per-lane partial max (tree, in-register only)
      float mb4[4];
#pragma unroll
      for (int bb = 0; bb < 4; ++bb)
        mb4[bb] = fmaxf(fmaxf(st[i][bb][0], st[i][bb][1]),
                        fmaxf(st[i][bb][2], st[i][bb][3]));
      float tpart = fmaxf(fmaxf(mb4[0], mb4[1]), fmaxf(mb4[2], mb4[3]));

      // shfl-free deferred check: rescale only if some lane's partial max
      // exceeds m_+7 (then do the full cross-lane reduction, exact).
      if (!__all(tpart <= m_[i] + 7.0f)) {
        float tmax = tpart;
        tmax = fmaxf(tmax, __shfl_xor(tmax, 16));
        tmax = fmaxf(tmax, __shfl_xor(tmax, 32));
        const float mnew = fmaxf(m_[i], tmax);
        const float corr = fexp2(m_[i] - mnew);
        l_[i] *= corr;
        float cr[4];
#pragma unroll
        for (int r = 0; r < 4; ++r) cr[r] = __shfl(corr, 4 * g + r);
#pragma unroll
        for (int j = 0; j < 4; ++j) {
          acc[i][j][0] *= cr[0]; acc[i][j][1] *= cr[1];
          acc[i][j][2] *= cr[2]; acc[i][j][3] *= cr[3];
        }
        m_[i] = mnew;
      }

      // exp2 + pack + P -> LDS ; l_ accumulates PARTIAL (no shfl)
      char* Pi = myP + i * 2048;
      float lsb[4];
#pragma unroll
      for (int bb = 0; bb < 4; ++bb) {
        float p0 = fexp2(st[i][bb][0] - m_[i]), p1 = fexp2(st[i][bb][1] - m_[i]);
        float p2 = fexp2(st[i][bb][2] - m_[i]), p3 = fexp2(st[i][bb][3] - m_[i]);
        lsb[bb] = (p0 + p1) + (p2 + p3);
        bf16x2 w0 = {(__bf16)p0, (__bf16)p1};
        bf16x2 w1 = {(__bf16)p2, (__bf16)p3};
        *(uint2*)(Pi + qi * 128 + ((32 * bb + 8 * g) ^ swz)) =
            make_uint2(__builtin_bit_cast(unsigned int, w0),
                       __builtin_bit_cast(unsigned int, w1));
      }
      l_[i] += (lsb[0] + lsb[1]) + (lsb[2] + lsb[3]);

      bf16x8 pa0 = *(bf16x8*)(Pi + qi * 128 + ((16 * g) ^ swz));
      bf16x8 pa1 = *(bf16x8*)(Pi + qi * 128 + ((64 + 16 * g) ^ swz));
      __builtin_amdgcn_s_setprio(1);
#pragma unroll
      for (int j = 0; j < 4; ++j) {
        acc[i][j] = mfma16(pa0, vf[j][0], acc[i][j]);
        acc[i][j] = mfma16(pa1, vf[j][1], acc[i][j]);
      }
      __builtin_amdgcn_s_setprio(0);
    }
  };

  auto run_mgroup = [&](int m) {
    const int q0w = 128 * m + cg * 64 + rg * 32;  // this wave's 32 rows

    bf16x8 qf[2][2];
#pragma unroll
    for (int i = 0; i < 2; ++i) {
      qf[i][0] = *(const bf16x8*)(Qp + (q0w + i * 16 + qi) * DK + 8 * g);
      qf[i][1] = *(const bf16x8*)(Qp + (q0w + i * 16 + qi) * DK + 32 + 8 * g);
    }
    f32x4 acc[2][4];
#pragma unroll
    for (int i = 0; i < 2; ++i)
#pragma unroll
      for (int j = 0; j < 4; ++j) acc[i][j] = (f32x4){0.f, 0.f, 0.f, 0.f};
    float m_[2] = {-1e30f, -1e30f}, l_[2] = {0.f, 0.f};  // l_ = lane PARTIAL

    __syncthreads();  // protect LDS from previous m-group's readers
    stage(0, 0);
    if (m >= 1) stage(1, 1);

    // full intervals t < m: 2 tiles in flight, counted wait (never drain 0)
    for (int t = 0; t < m; ++t) {
      asm volatile("s_waitcnt vmcnt(4)" ::: "memory");  // tile t staged
      __builtin_amdgcn_s_barrier();
      if (t + 2 <= m) {
        int nx = t + 2;
        nx -= (nx / 3) * 3;  // (t+2)%3
        stage(nx, t + 2);
      }
      int cb = t - (t / 3) * 3;
      tile(cb, false, 0, q0w, qf, acc, m_, l_);
    }
    // final interval t = m: full drain, guard + mask
    asm volatile("s_waitcnt vmcnt(0)" ::: "memory");
    __builtin_amdgcn_s_barrier();
    {
      int cb = m - (m / 3) * 3;
      if (!(par == 1 && cg == 0))
        tile(cb, par == cg, (2 * m + par) * 64, q0w, qf, acc, m_, l_);
    }

    // ---- exact merge of parity states (through free K LDS) ----
    __syncthreads();
    char* Mb = smem + (cg * 2 + rg) * 9216 + lane * 144;
    if (par == 1) {
#pragma unroll
      for (int i = 0; i < 2; ++i)
#pragma unroll
        for (int j = 0; j < 4; ++j)
          *(f32x4*)(Mb + (i * 4 + j) * 16) = acc[i][j];
      *(float*)(Mb + 128) = m_[0];
      *(float*)(Mb + 132) = m_[1];
      *(float*)(Mb + 136) = l_[0];
      *(float*)(Mb + 140) = l_[1];
    }
    __syncthreads();
    if (par == 0) {
#pragma unroll
      for (int i = 0; i < 2; ++i) {
        float m1 = *(const float*)(Mb + 128 + i * 4);
        float l1 = *(const float*)(Mb + 136 + i * 4);
        const float mn = fmaxf(m_[i], m1);
        const float c0 = fexp2(m_[i] - mn), c1 = fexp2(m1 - mn);
        float lt = l_[i] * c0 + l1 * c1;      // per-lane partial
        lt += __shfl_xor(lt, 16);             // reduce across g once
        lt += __shfl_xor(lt, 32);
        float cr0[4], cr1[4], ir[4];
        const float inv = 1.f / lt;
#pragma unroll
        for (int r = 0; r < 4; ++r) {
          cr0[r] = __shfl(c0, 4 * g + r);
          cr1[r] = __shfl(c1, 4 * g + r);
          ir[r] = __shfl(inv, 4 * g + r);
        }
#pragma unroll
        for (int j = 0; j < 4; ++j) {
          f32x4 a1 = *(const f32x4*)(Mb + (i * 4 + j) * 16);
#pragma unroll
          for (int r = 0; r < 4; ++r) {
            float v = acc[i][j][r] * cr0[r] + a1[r] * cr1[r];
            AOs[((size_t)b * Sq + q0w + i * 16 + 4 * g + r) * Dm + h * DK +
                16 * j + qi] = bfb(v * ir[r]);
          }
        }
      }
    }
  };

  run_mgroup(15 - j8);  // big m-group first
  run_mgroup(j8);
}

// ================================ launch ===================================
extern "C" void kernel_launch(void* const* d_in, const int* in_sizes, int n_in,
                              void* d_out, int out_size, void* d_ws,
                              size_t ws_size, hipStream_t stream) {
  const float* x  = (const float*)d_in[0];
  const float* Wq = (const float*)d_in[1];
  const float* Wk = (const float*)d_in[2];
  const float* Wv = (const float*)d_in[3];
  const float* Wo = (const float*)d_in[4];
  float* out = (float*)d_out;

  char* w = (char*)d_ws;
  __bf16* Qb  = (__bf16*)(w);                 // 8 MB [bh][s][64] (pre-scaled)
  __bf16* Kb  = (__bf16*)(w + (8u << 20));    // 8 MB
  __bf16* Vt  = (__bf16*)(w + (16u << 20));   // 8 MB [bh][64][s]
  __bf16* AOb = (__bf16*)(w + (24u << 20));   // 8 MB [B,S,D]
  __bf16* xb  = (__bf16*)(w + (32u << 20));   // 8 MB [4096][1024]
  __bf16* Wt  = (__bf16*)(w + (40u << 20));   // 4 x 2 MB [n][k]
  float2* tbl = (float2*)(w + (48u << 20));   // 512 KB

  prep_kernel<<<6400, 256, 0, stream>>>(x, Wq, Wk, Wv, Wo, xb, Wt, tbl);
  gemm_qkv<<<768, 256, 0, stream>>>(xb, Wt, tbl, Qb, Kb, Vt);
  attn_kernel<<<256, 512, 131072, stream>>>(Qb, Kb, Vt, AOb);
  gemm_o<<<256, 256, 0, stream>>>(AOb, Wt + (size_t)3 * Dm * Dm, out);
}

// Round 22
// 94.492 us; speedup vs baseline: 1.8015x; 1.0133x over previous
//
#include <hip/hip_runtime.h>
#include <cmath>

// ---------------------------------------------------------------------------
// MHA forward, bf16-MFMA everywhere.  (Best-measured configuration: r19.)
//   prep (1 kernel): x->bf16 ; W* -> bf16 transposed [n][k] ; RoPE table
//   gemm_qkv (768 blk, XCD m-band swizzled): BK=32, TRIPLE-buffered pipeline,
//       counted s_waitcnt vmcnt(4) + raw s_barrier (no vmcnt(0) drain in the
//       main loop); xb@Wt -> Q/K (RoPE epilogue) / V-transpose
//   attn: causal flash attn, 256 blk x 8 waves; 2-buffer K/V staging with
//       __syncthreads; shfl-free softmax; raw v_exp_f32; exact parity merge
//   gemm_o (256 blk, swizzled, same pipelined core): AOb@Wto -> out fp32
// B=2 S=2048 D=1024 H=16 dk=64
// ---------------------------------------------------------------------------

constexpr int Bz = 2, Sq = 2048, Dm = 1024, Hh = 16, DK = 64;
constexpr int Mrows = Bz * Sq;  // 4096

typedef __attribute__((ext_vector_type(4))) float f32x4;
typedef __attribute__((ext_vector_type(2))) __bf16 bf16x2;
typedef __attribute__((ext_vector_type(4))) __bf16 bf16x4;
typedef __attribute__((ext_vector_type(8))) __bf16 bf16x8;
typedef __attribute__((ext_vector_type(8))) short short8v;

__device__ __forceinline__ f32x4 mfma16(bf16x8 a, bf16x8 b, f32x4 c) {
  return __builtin_amdgcn_mfma_f32_16x16x32_bf16(a, b, c, 0, 0, 0);
}
__device__ __forceinline__ short bfb(float x) {
  return __builtin_bit_cast(short, (__bf16)x);
}
// raw v_exp_f32 (2^x); args here are <= ~0 or large-negative -> in range
__device__ __forceinline__ float fexp2(float x) {
#if __has_builtin(__builtin_amdgcn_exp2f)
  return __builtin_amdgcn_exp2f(x);
#else
  float r;
  asm("v_exp_f32 %0, %1" : "=v"(r) : "v"(x));
  return r;
#endif
}
// async global->LDS, 16 B per lane; lds ptr must be wave-uniform
__device__ __forceinline__ void gload16(const void* g, void* l) {
  __builtin_amdgcn_global_load_lds(
      (__attribute__((address_space(1))) void*)g,
      (__attribute__((address_space(3))) void*)l, 16, 0, 0);
}

// ============================ prep (fused) =================================
// blocks [0,2048): x->bf16 ; [2048,6144): W transpose ; [6144,6400): RoPE tbl
__global__ __launch_bounds__(256) void prep_kernel(
    const float* __restrict__ x, const float* __restrict__ Wq,
    const float* __restrict__ Wk, const float* __restrict__ Wv,
    const float* __restrict__ Wo, __bf16* __restrict__ xb,
    __bf16* __restrict__ Wt, float2* __restrict__ tbl) {
  __shared__ float tile[32][33];
  const int bid = blockIdx.x, tid = threadIdx.x;
  if (bid < 2048) {
    int t = bid * 256 + tid;
    const float4* p = (const float4*)x + (size_t)t * 2;
    float4 a = p[0], b = p[1];
    bf16x8 o = {(__bf16)a.x, (__bf16)a.y, (__bf16)a.z, (__bf16)a.w,
                (__bf16)b.x, (__bf16)b.y, (__bf16)b.z, (__bf16)b.w};
    *(bf16x8*)(xb + (size_t)t * 8) = o;
  } else if (bid < 6144) {
    int wid = bid - 2048;
    int z = wid >> 10, rem = wid & 1023;
    const float* W = (z == 0) ? Wq : (z == 1) ? Wk : (z == 2) ? Wv : Wo;
    __bf16* out = Wt + (size_t)z * Dm * Dm;
    int r0 = (rem >> 5) * 32, c0 = (rem & 31) * 32;
    int r = tid >> 3, c4 = (tid & 7) * 4;
    float4 v = *(const float4*)&W[(size_t)(r0 + r) * Dm + c0 + c4];
    tile[r][c4] = v.x; tile[r][c4 + 1] = v.y;
    tile[r][c4 + 2] = v.z; tile[r][c4 + 3] = v.w;
    __syncthreads();
    int nl = tid >> 3, k4 = (tid & 7) * 4;
    bf16x4 o = {(__bf16)tile[k4][nl], (__bf16)tile[k4 + 1][nl],
                (__bf16)tile[k4 + 2][nl], (__bf16)tile[k4 + 3][nl]};
    *(bf16x4*)&out[(size_t)(c0 + nl) * Dm + r0 + k4] = o;
  } else {
    int t = (bid - 6144) * 256 + tid;  // 65536
    int s = t >> 5, j = t & 31;
    float inv = exp2f(-13.287712379549449f * (1.0f / 32.0f) * (float)j);
    float sn, cs;
    sincosf((float)s * inv, &sn, &cs);
    tbl[t] = make_float2(cs, sn);
  }
}

// ========================= bf16 MFMA GEMM core =============================
// acc[4][4] = A[m0..+128][:] @ Bt[n0..+128][:]^T. BK=32, TRIPLE-buffered.
// Per interval: s_waitcnt vmcnt(4) (tile t's loads done; t+1 stays in
// flight) -> s_barrier -> issue stage(t+2) -> compute tile t. The vmcnt(0)
// drain happens only for the final tile. LDS: As[3][128][32] @0 (24 KB),
// Bs[3][128][32] @24K (24 KB) = 48 KB.
__device__ __forceinline__ void gemm_core(const __bf16* __restrict__ A,
                                          const __bf16* __restrict__ Bt,
                                          char* smem, f32x4 (&acc)[4][4],
                                          int m0, int n0, int tid) {
  short* As = (short*)smem;             // [3][128][32]
  short* Bs = (short*)(smem + 24576);   // [3][128][32]
  const int lane = tid & 63, w = tid >> 6;
  const int qi = lane & 15, c = lane >> 4;
  const int wr = w >> 1, wc = w & 1;
  const int srow = lane >> 2;                        // 0..15
  const int scol = (((lane & 3) ^ (srow & 3)) * 8);  // swizzled SOURCE col
  const __bf16* gA = A + (size_t)(m0 + w * 16 + srow) * Dm + scol;
  const __bf16* gB = Bt + (size_t)(n0 + w * 16 + srow) * Dm + scol;
  short* lA = As + w * 512;  // wave-uniform LDS dest (buffer 0 slot)
  short* lB = Bs + w * 512;
  const int cx = (c ^ (qi & 3)) * 8;  // swizzled read col (row&3 == qi&3)

  auto stage = [&](int cb, int k0) {
    gload16(gA + k0, lA + cb * 4096);
    gload16(gA + (size_t)64 * Dm + k0, lA + cb * 4096 + 2048);
    gload16(gB + k0, lB + cb * 4096);
    gload16(gB + (size_t)64 * Dm + k0, lB + cb * 4096 + 2048);
  };
  auto compute = [&](int cb) {
    bf16x8 af[4], bfv[4];
#pragma unroll
    for (int i = 0; i < 4; ++i) {
      af[i]  = *(bf16x8*)(As + cb * 4096 + (wr * 64 + i * 16 + qi) * 32 + cx);
      bfv[i] = *(bf16x8*)(Bs + cb * 4096 + (wc * 64 + i * 16 + qi) * 32 + cx);
    }
#pragma unroll
    for (int i = 0; i < 4; ++i)
#pragma unroll
      for (int j = 0; j < 4; ++j) acc[i][j] = mfma16(af[i], bfv[j], acc[i][j]);
  };

#pragma unroll
  for (int i = 0; i < 4; ++i)
#pragma unroll
    for (int j = 0; j < 4; ++j) acc[i][j] = (f32x4){0.f, 0.f, 0.f, 0.f};

  stage(0, 0);
  stage(1, 32);
  int cur = 0;
  for (int k0 = 0; k0 < Dm - 32; k0 += 32) {
    asm volatile("s_waitcnt vmcnt(4)" ::: "memory");  // tile t staged
    __builtin_amdgcn_s_barrier();                     // ...on all waves
    if (k0 + 64 < Dm) {
      int nx = cur + 2;
      if (nx >= 3) nx -= 3;
      stage(nx, k0 + 64);  // into buffer freed at iter t-1; stays in flight
    }
    compute(cur);
    if (++cur == 3) cur = 0;
  }
  asm volatile("s_waitcnt vmcnt(0)" ::: "memory");  // final tile
  __builtin_amdgcn_s_barrier();
  compute(cur);
}

// ===================== fused QKV GEMM (flattened grid) =====================
// 768 blocks. XCD m-band swizzle: xcd=bid&7 owns m-blocks 4*xcd..+3; within
// XCD order is m-inner so B tiles get back-to-back L2 reuse.
// z==0: Q + RoPE (scaled 0.125*log2e). z==1: K + RoPE. z==2: Vt[bh][d][s].
__global__ __launch_bounds__(256) void gemm_qkv(
    const __bf16* __restrict__ xb, const __bf16* __restrict__ Wt,
    const float2* __restrict__ tbl, __bf16* __restrict__ Qb,
    __bf16* __restrict__ Kb, __bf16* __restrict__ Vt) {
  __shared__ __align__(16) char smem[49152];
  const int tid = threadIdx.x;
  const int bid = blockIdx.x;
  const int xcd = bid & 7, r8 = bid >> 3;          // r8 in [0,96)
  const int mb = (xcd << 2) | (r8 & 3);            // m-block 0..31
  const int zn = r8 >> 2;                          // 0..23
  const int z = zn >> 3, nb = zn & 7;
  const int m0 = mb * 128, n0 = nb * 128;

  f32x4 acc[4][4];
  gemm_core(xb, Wt + (size_t)z * Dm * Dm, smem, acc, m0, n0, tid);

  const int lane = tid & 63, w = tid >> 6;
  const int qi = lane & 15, c = lane >> 4;
  const int wr = w >> 1, wc = w & 1;

  if (z == 2) {  // Vt[bh][d][s]
    __syncthreads();
    short* T = (short*)smem;  // [128][136] padded
#pragma unroll
    for (int i = 0; i < 4; ++i)
#pragma unroll
      for (int j = 0; j < 4; ++j) {
        int nl = wc * 64 + j * 16 + qi;
        int mbr = wr * 64 + i * 16 + c * 4;
        bf16x4 pk = {(__bf16)acc[i][j][0], (__bf16)acc[i][j][1],
                     (__bf16)acc[i][j][2], (__bf16)acc[i][j][3]};
        *(bf16x4*)(T + nl * 136 + mbr) = pk;
      }
    __syncthreads();
    short* C = (short*)Vt;
    int b = m0 >> 11, sb = m0 & (Sq - 1);
#pragma unroll
    for (int it = 0; it < 8; ++it) {
      int f = tid + it * 256;
      int nl = f >> 4, mc = f & 15;
      short8v v = *(short8v*)(T + nl * 136 + mc * 8);
      int ng = n0 + nl;
      int d = ng & (DK - 1), h = (ng >> 6) & (Hh - 1);
      *(short8v*)(C + ((size_t)(b * Hh + h) * DK + d) * Sq + sb + mc * 8) = v;
    }
  } else {  // Q or K: stage raw bf16, RoPE on re-read (pairs in-thread)
    __syncthreads();
    short* T = (short*)smem;  // [128][136]
#pragma unroll
    for (int i = 0; i < 4; ++i)
#pragma unroll
      for (int j = 0; j < 4; ++j) {
        int nl = wc * 64 + j * 16 + qi;
        int mbr = wr * 64 + i * 16 + c * 4;
#pragma unroll
        for (int rr = 0; rr < 4; ++rr)
          T[(mbr + rr) * 136 + nl] = bfb(acc[i][j][rr]);
      }
    __syncthreads();
    const float sc = (z == 0) ? 0.18033688011112042f : 1.0f;  // 0.125*log2e
    short* C = (short*)((z == 0) ? Qb : Kb);
    const int b = m0 >> 11;
#pragma unroll
    for (int it = 0; it < 8; ++it) {
      int f = tid + it * 256;
      int ml = f >> 4, c16 = f & 15;
      bf16x8 v = *(bf16x8*)(T + ml * 136 + c16 * 8);
      int s = (m0 + ml) & (Sq - 1);
      int n = n0 + c16 * 8;
      int d0 = n & (DK - 1), h = (n >> 6) & (Hh - 1);
      int jj = d0 >> 1;
      float4 t01 = *(const float4*)&tbl[s * 32 + jj];      // cos0,sin0,cos1,sin1
      float4 t23 = *(const float4*)&tbl[s * 32 + jj + 2];
      bf16x8 o;
      float x0 = (float)v[0], y0 = (float)v[1];
      o[0] = (__bf16)((x0 * t01.x - y0 * t01.y) * sc);
      o[1] = (__bf16)((y0 * t01.x + x0 * t01.y) * sc);
      float x1 = (float)v[2], y1 = (float)v[3];
      o[2] = (__bf16)((x1 * t01.z - y1 * t01.w) * sc);
      o[3] = (__bf16)((y1 * t01.z + x1 * t01.w) * sc);
      float x2 = (float)v[4], y2 = (float)v[5];
      o[4] = (__bf16)((x2 * t23.x - y2 * t23.y) * sc);
      o[5] = (__bf16)((y2 * t23.x + x2 * t23.y) * sc);
      float x3 = (float)v[6], y3 = (float)v[7];
      o[6] = (__bf16)((x3 * t23.z - y3 * t23.w) * sc);
      o[7] = (__bf16)((y3 * t23.z + x3 * t23.w) * sc);
      *(bf16x8*)(C + ((size_t)(b * Hh + h) * Sq + s) * DK + d0) = o;
    }
  }
}

// ============================== O GEMM =====================================
// 256 blocks, XCD m-band swizzle. fp32 output via 2-pass LDS transpose.
__global__ __launch_bounds__(256) void gemm_o(
    const __bf16* __restrict__ AOb, const __bf16* __restrict__ Wto,
    float* __restrict__ C) {
  __shared__ __align__(16) char smem[49152];
  const int tid = threadIdx.x;
  const int bid = blockIdx.x;
  const int xcd = bid & 7, r8 = bid >> 3;          // r8 in [0,32)
  const int mb = (xcd << 2) | (r8 & 3);
  const int nb = r8 >> 2;
  const int m0 = mb * 128, n0 = nb * 128;

  f32x4 acc[4][4];
  gemm_core(AOb, Wto, smem, acc, m0, n0, tid);

  const int lane = tid & 63, w = tid >> 6;
  const int qi = lane & 15, c = lane >> 4;
  const int wr = w >> 1, wc = w & 1;
  float* T32 = (float*)smem;  // [64][132] = 33792 B

#pragma unroll
  for (int pass = 0; pass < 2; ++pass) {
    __syncthreads();
#pragma unroll
    for (int i2 = 0; i2 < 2; ++i2) {
      int i = pass * 2 + i2;
#pragma unroll
      for (int j = 0; j < 4; ++j) {
        int nl = wc * 64 + j * 16 + qi;
        int cm = wr * 32 + i2 * 16 + c * 4;
#pragma unroll
        for (int rr = 0; rr < 4; ++rr)
          T32[(cm + rr) * 132 + nl] = acc[i][j][rr];
      }
    }
    __syncthreads();
#pragma unroll
    for (int it = 0; it < 8; ++it) {
      int f = tid + it * 256;           // 0..2047
      int cm = f >> 5, c4 = f & 31;
      float4 v = *(float4*)(T32 + cm * 132 + c4 * 4);
      int m = m0 + (cm >> 5) * 64 + pass * 32 + (cm & 31);
      *(float4*)&C[(size_t)m * Dm + n0 + c4 * 4] = v;
    }
  }
}

// ======================= Flash attention (bf16 MFMA) ========================
// 256 blocks x 8 waves (512 thr). wave -> (cg, rg, par); 32 q-rows per wave.
// m-group m: chunks 2m/2m+1, both need m+1 staged 128-k tiles; serial
// m-groups (15-j, j) -> uniform 17 intervals. SHFL-FREE common path:
// per-lane deferred-max check; l_ = per-lane PARTIAL row-sum reduced once
// at merge; raw v_exp_f32. Exact parity merge per m-group. XCD-partitioned.
// LDS (96 KB): K[2][16K], V[2][16K], P[8][4K]. 1 block/CU, grid 256.
__global__ __launch_bounds__(512, 2) void attn_kernel(
    const __bf16* __restrict__ Qb, const __bf16* __restrict__ Kb,
    const __bf16* __restrict__ Vt, __bf16* __restrict__ AOb) {
  extern __shared__ __align__(16) char smem[];

  const int bid = blockIdx.x;            // 256
  const int xcd = bid & 7;               // hw round-robin -> XCD id (heuristic)
  const int idx = bid >> 3;              // 0..31 within XCD
  const int bh = (xcd << 2) | (idx >> 3);
  const int j8 = idx & 7;                // m-groups: 15-j8 then j8
  const int b = bh >> 4, h = bh & (Hh - 1);
  const int tid = threadIdx.x, lane = tid & 63, w = tid >> 6;  // w 0..7
  const int cg = w & 1, rg = (w >> 1) & 1, par = w >> 2;
  const int g = lane >> 4, qi = lane & 15;

  const __bf16* Qp = Qb + (size_t)bh * Sq * DK;
  const __bf16* Kp = Kb + (size_t)bh * Sq * DK;
  const __bf16* Vp = Vt + (size_t)bh * DK * Sq;

  char* myP = smem + 65536 + w * 4096;   // [2 i][16 rows][128 B]
  const int swz = (qi & 7) << 4;
  const int srow8 = lane >> 3, scol8 = lane & 7;
  const int srow4 = lane >> 4, scol16 = lane & 15;
  short* AOs = (short*)AOb;

  // stage K[128][64] + V[64][128] of 128-k tile t into buffer cb
  auto stage = [&](int cb, int t) {
    const int kbase = t * 128;
    char* Kd = smem + cb * 16384;
    char* Vd = smem + 32768 + cb * 16384;
#pragma unroll
    for (int s2 = 0; s2 < 2; ++s2) {
      int seg = w * 2 + s2;
      int r = seg * 8 + srow8;                       // K row 0..127
      gload16(Kp + (size_t)(kbase + r) * DK + ((scol8 ^ (r & 7)) << 3),
              Kd + seg * 1024);
      int d = seg * 4 + srow4;                       // V row 0..63
      int ss = (scol16 & 8) | ((scol16 ^ (d & 7)) & 7);  // keep k-half bit
      gload16(Vp + (size_t)d * Sq + kbase + ss * 8, Vd + seg * 1024);
    }
  };

  // one interval: this wave's 64-k parity half x its 32 q-rows
  auto tile = [&](int cb, bool domask, int kbase, int q0w,
                  const bf16x8 (&qf)[2][2], f32x4 (&acc)[2][4],
                  float (&m_)[2], float (&l_)[2]) {
    const char* Kt = smem + cb * 16384 + par * 8192;
    const char* Vv = smem + 32768 + cb * 16384;
    const int vpo = par * 128;

    bf16x8 kf[4][2];
#pragma unroll
    for (int bb = 0; bb < 4; ++bb) {
      int rr = 16 * bb + qi;
      kf[bb][0] = *(const bf16x8*)(Kt + rr * 128 + ((g ^ (rr & 7)) << 4));
      kf[bb][1] = *(const bf16x8*)(Kt + rr * 128 + (((g + 4) ^ (rr & 7)) << 4));
    }
    bf16x8 vf[4][2];
#pragma unroll
    for (int j = 0; j < 4; ++j) {
      int rr = 16 * j + qi;
      vf[j][0] = *(const bf16x8*)(Vv + rr * 256 + vpo + ((g ^ (rr & 7)) << 4));
      vf[j][1] =
          *(const bf16x8*)(Vv + rr * 256 + vpo + (((g + 4) ^ (rr & 7)) << 4));
    }

    // ---- QK^T for BOTH 16-row groups (group1 overlaps group0 softmax) ----
    f32x4 st[2][4];
    __builtin_amdgcn_s_setprio(1);
#pragma unroll
    for (int i = 0; i < 2; ++i)
#pragma unroll
      for (int bb = 0; bb < 4; ++bb) {
        st[i][bb] = mfma16(kf[bb][0], qf[i][0], (f32x4){0.f, 0.f, 0.f, 0.f});
        st[i][bb] = mfma16(kf[bb][1], qf[i][1], st[i][bb]);
      }
    __builtin_amdgcn_s_setprio(0);

    if (domask) {
#pragma unroll
      for (int i = 0; i < 2; ++i)
#pragma unroll
        for (int bb = 0; bb < 4; ++bb)
#pragma unroll
          for (int r = 0; r < 4; ++r)
            if (kbase + 16 * bb + 4 * g + r > q0w + i * 16 + qi)
              st[i][bb][r] = -1e30f;
    }

#pragma unroll
    for (int i = 0; i < 2; ++i) {
      // per-lane partial max (tree, in-register only)
      float mb4[4];
#pragma unroll
      for (int bb = 0; bb < 4; ++bb)
        mb4[bb] = fmaxf(fmaxf(st[i][bb][0], st[i][bb][1]),
                        fmaxf(st[i][bb][2], st[i][bb][3]));
      float tpart = fmaxf(fmaxf(mb4[0], mb4[1]), fmaxf(mb4[2], mb4[3]));

      // shfl-free deferred check: rescale only if some lane's partial max
      // exceeds m_+7 (then do the full cross-lane reduction, exact).
      if (!__all(tpart <= m_[i] + 7.0f)) {
        float tmax = tpart;
        tmax = fmaxf(tmax, __shfl_xor(tmax, 16));
        tmax = fmaxf(tmax, __shfl_xor(tmax, 32));
        const float mnew = fmaxf(m_[i], tmax);
        const float corr = fexp2(m_[i] - mnew);
        l_[i] *= corr;
        float cr[4];
#pragma unroll
        for (int r = 0; r < 4; ++r) cr[r] = __shfl(corr, 4 * g + r);
#pragma unroll
        for (int j = 0; j < 4; ++j) {
          acc[i][j][0] *= cr[0]; acc[i][j][1] *= cr[1];
          acc[i][j][2] *= cr[2]; acc[i][j][3] *= cr[3];
        }
        m_[i] = mnew;
      }

      // exp2 + pack + P -> LDS ; l_ accumulates PARTIAL (no shfl)
      char* Pi = myP + i * 2048;
      float lsb[4];
#pragma unroll
      for (int bb = 0; bb < 4; ++bb) {
        float p0 = fexp2(st[i][bb][0] - m_[i]), p1 = fexp2(st[i][bb][1] - m_[i]);
        float p2 = fexp2(st[i][bb][2] - m_[i]), p3 = fexp2(st[i][bb][3] - m_[i]);
        lsb[bb] = (p0 + p1) + (p2 + p3);
        bf16x2 w0 = {(__bf16)p0, (__bf16)p1};
        bf16x2 w1 = {(__bf16)p2, (__bf16)p3};
        *(uint2*)(Pi + qi * 128 + ((32 * bb + 8 * g) ^ swz)) =
            make_uint2(__builtin_bit_cast(unsigned int, w0),
                       __builtin_bit_cast(unsigned int, w1));
      }
      l_[i] += (lsb[0] + lsb[1]) + (lsb[2] + lsb[3]);

      bf16x8 pa0 = *(bf16x8*)(Pi + qi * 128 + ((16 * g) ^ swz));
      bf16x8 pa1 = *(bf16x8*)(Pi + qi * 128 + ((64 + 16 * g) ^ swz));
      __builtin_amdgcn_s_setprio(1);
#pragma unroll
      for (int j = 0; j < 4; ++j) {
        acc[i][j] = mfma16(pa0, vf[j][0], acc[i][j]);
        acc[i][j] = mfma16(pa1, vf[j][1], acc[i][j]);
      }
      __builtin_amdgcn_s_setprio(0);
    }
  };

  auto run_mgroup = [&](int m) {
    const int q0w = 128 * m + cg * 64 + rg * 32;  // this wave's 32 rows

    bf16x8 qf[2][2];
#pragma unroll
    for (int i = 0; i < 2; ++i) {
      qf[i][0] = *(const bf16x8*)(Qp + (q0w + i * 16 + qi) * DK + 8 * g);
      qf[i][1] = *(const bf16x8*)(Qp + (q0w + i * 16 + qi) * DK + 32 + 8 * g);
    }
    f32x4 acc[2][4];
#pragma unroll
    for (int i = 0; i < 2; ++i)
#pragma unroll
      for (int j = 0; j < 4; ++j) acc[i][j] = (f32x4){0.f, 0.f, 0.f, 0.f};
    float m_[2] = {-1e30f, -1e30f}, l_[2] = {0.f, 0.f};  // l_ = lane PARTIAL

    __syncthreads();  // protect LDS from previous m-group's readers
    stage(0, 0);

    int cur = 0;
    for (int t = 0; t < m; ++t) {  // full intervals: no mask, no skip
      __syncthreads();             // buf[cur] staged
      stage(cur ^ 1, t + 1);
      tile(cur, false, 0, q0w, qf, acc, m_, l_);
      cur ^= 1;
    }
    __syncthreads();
    // final tile t=m: ktv = 2m+par vs qc = 2m+cg
    if (!(par == 1 && cg == 0))
      tile(cur, par == cg, (2 * m + par) * 64, q0w, qf, acc, m_, l_);

    // ---- exact merge of parity states (through free K/V LDS) ----
    __syncthreads();
    char* Mb = smem + (cg * 2 + rg) * 9216 + lane * 144;
    if (par == 1) {
#pragma unroll
      for (int i = 0; i < 2; ++i)
#pragma unroll
        for (int j = 0; j < 4; ++j)
          *(f32x4*)(Mb + (i * 4 + j) * 16) = acc[i][j];
      *(float*)(Mb + 128) = m_[0];
      *(float*)(Mb + 132) = m_[1];
      *(float*)(Mb + 136) = l_[0];
      *(float*)(Mb + 140) = l_[1];
    }
    __syncthreads();
    if (par == 0) {
#pragma unroll
      for (int i = 0; i < 2; ++i) {
        float m1 = *(const float*)(Mb + 128 + i * 4);
        float l1 = *(const float*)(Mb + 136 + i * 4);
        const float mn = fmaxf(m_[i], m1);
        const float c0 = fexp2(m_[i] - mn), c1 = fexp2(m1 - mn);
        float lt = l_[i] * c0 + l1 * c1;      // per-lane partial
        lt += __shfl_xor(lt, 16);             // reduce across g once
        lt += __shfl_xor(lt, 32);
        float cr0[4], cr1[4], ir[4];
        const float inv = 1.f / lt;
#pragma unroll
        for (int r = 0; r < 4; ++r) {
          cr0[r] = __shfl(c0, 4 * g + r);
          cr1[r] = __shfl(c1, 4 * g + r);
          ir[r] = __shfl(inv, 4 * g + r);
        }
#pragma unroll
        for (int j = 0; j < 4; ++j) {
          f32x4 a1 = *(const f32x4*)(Mb + (i * 4 + j) * 16);
#pragma unroll
          for (int r = 0; r < 4; ++r) {
            float v = acc[i][j][r] * cr0[r] + a1[r] * cr1[r];
            AOs[((size_t)b * Sq + q0w + i * 16 + 4 * g + r) * Dm + h * DK +
                16 * j + qi] = bfb(v * ir[r]);
          }
        }
      }
    }
  };

  run_mgroup(15 - j8);  // big m-group first
  run_mgroup(j8);
}

// ================================ launch ===================================
extern "C" void kernel_launch(void* const* d_in, const int* in_sizes, int n_in,
                              void* d_out, int out_size, void* d_ws,
                              size_t ws_size, hipStream_t stream) {
  const float* x  = (const float*)d_in[0];
  const float* Wq = (const float*)d_in[1];
  const float* Wk = (const float*)d_in[2];
  const float* Wv = (const float*)d_in[3];
  const float* Wo = (const float*)d_in[4];
  float* out = (float*)d_out;

  char* w = (char*)d_ws;
  __bf16* Qb  = (__bf16*)(w);                 // 8 MB [bh][s][64] (pre-scaled)
  __bf16* Kb  = (__bf16*)(w + (8u << 20));    // 8 MB
  __bf16* Vt  = (__bf16*)(w + (16u << 20));   // 8 MB [bh][64][s]
  __bf16* AOb = (__bf16*)(w + (24u << 20));   // 8 MB [B,S,D]
  __bf16* xb  = (__bf16*)(w + (32u << 20));   // 8 MB [4096][1024]
  __bf16* Wt  = (__bf16*)(w + (40u << 20));   // 4 x 2 MB [n][k]
  float2* tbl = (float2*)(w + (48u << 20));   // 512 KB

  prep_kernel<<<6400, 256, 0, stream>>>(x, Wq, Wk, Wv, Wo, xb, Wt, tbl);
  gemm_qkv<<<768, 256, 0, stream>>>(xb, Wt, tbl, Qb, Kb, Vt);
  attn_kernel<<<256, 512, 98304, stream>>>(Qb, Kb, Vt, AOb);
  gemm_o<<<256, 256, 0, stream>>>(AOb, Wt + (size_t)3 * Dm * Dm, out);
}